// Round 7
// baseline (180.809 us; speedup 1.0000x reference)
//
#include <hip/hip_runtime.h>

// BLAMem: truncated tensor-algebra (depth 4, C=8) log-signature memory.
// Round-14: ONE kernel, 5 roles, producer-consumer FLAG DATAFLOW (no grid barrier).
// Evidence: R6 proved the mechanism (sc0 sc1 write-through + flag after vmcnt-drained
// __syncthreads + timeout poll) at absmax 0.0 with ~0 sync cost. R1/R6 arithmetic says
// the 5-kernel pipeline's remaining ~80us is per-dispatch overhead (~10-15us x 5), not
// work (~25us) -- so the win is removing kernel boundaries, not barriers. Roles in
// blockIdx order (fold 256 | scan 128 | apply 1024 | gemv 147 | final 8): HW dispatches
// workgroups in-order, so freed slots always go to producers before waiting consumers
// -> no deadlock at any occupancy; every poll is timeout-protected anyway.
// Grid-barrier arc (R9-R12) is dead: fenced barriers cost ~45us each (L2 wb/inv
// sweeps); this design has NO fences and NO grid-wide rendezvous.
// Carried: NO atomic RMW; LDS rows padded to stride 9; FP summation orders
// bit-identical to the verified round-0/1/6 kernels.

#define MEM   4680   // 8 + 64 + 512 + 4096 (unpadded global layout)
#define NG    32     // groups per batch
#define TLEN  2048

#define P3OFF 72
#define P4OFF 648
#define SIGSZ 5256

// Coherence-point accessors (SYSTEM scope => sc0 sc1: bypass L1+L2, no fences).
__device__ __forceinline__ float ldc(const float* p) {
    return __hip_atomic_load(p, __ATOMIC_RELAXED, __HIP_MEMORY_SCOPE_SYSTEM);
}
__device__ __forceinline__ void stc(float* p, float v) {
    __hip_atomic_store(p, v, __ATOMIC_RELAXED, __HIP_MEMORY_SCOPE_SYSTEM);
}
__device__ __forceinline__ unsigned ldu(const unsigned* p) {
    return __hip_atomic_load(p, __ATOMIC_RELAXED, __HIP_MEMORY_SCOPE_SYSTEM);
}
__device__ __forceinline__ void stu(unsigned* p, unsigned v) {
    __hip_atomic_store(p, v, __ATOMIC_RELAXED, __HIP_MEMORY_SCOPE_SYSTEM);
}
#define SPIN_TIMEOUT 4000000ull   // ~40ms: any sync bug => wrong answer, never a hang

__device__ __forceinline__ void waitflag(const unsigned* f) {
    unsigned long long t0 = __builtin_amdgcn_s_memrealtime();
    while (ldu(f) == 0u) {
        __builtin_amdgcn_s_sleep(8);
        if (__builtin_amdgcn_s_memrealtime() - t0 > SPIN_TIMEOUT) break;
    }
}

// Load the 64 per-step increments for group (b,g) into sInc[512].
__device__ __forceinline__ void load_inc(const float* __restrict__ x, int b, int g,
                                         float* sInc, int tid) {
    for (int e = tid; e < 512; e += 256) {
        int s = e >> 3, c = e & 7;
        int t = g * 64 + s;
        float v;
        if (c < 7) {
            float cur  = x[(b * TLEN + t) * 7 + c];
            float prev = (t > 0) ? x[(b * TLEN + t - 1) * 7 + c] : 0.f;
            v = cur - prev;
        } else v = (t > 0) ? (1.f / 2047.f) : 0.f;
        sInc[e] = v;
    }
}

// Fold chunk-local signature (16 steps, closed form) into running padded product sA.
__device__ __forceinline__ void chunk_step(const float* dch, float* sA, float* U, int tid) {
    float* loc3 = U;
    float* loc2 = U + 576;
    float* loc1 = U + 640;
    const int i1 = tid >> 6, j1 = (tid >> 3) & 7, k1 = tid & 7;
    const int row1 = tid >> 3, row2 = row1 + 32;
    const int jk = tid & 63;
    const int pos2 = tid + 256, i2 = pos2 >> 6;
    float p1a = 0.f, l2a = 0.f, l3a = 0.f, p1b = 0.f, l2b = 0.f, l3b = 0.f;
    float Sa[8], Sb[8];
#pragma unroll
    for (int l = 0; l < 8; l++) { Sa[l] = 0.f; Sb[l] = 0.f; }
#pragma unroll
    for (int t = 0; t < 16; t++) {
        const float* dr = dch + t * 8;
        float di1 = dr[i1], di2 = dr[i2], dj = dr[j1], dk = dr[k1];
        float ga = l3a + dk * (l2a * 0.5f + dj * (p1a * (1.f/6.f) + di1 * (1.f/24.f)));
        float gb = l3b + dk * (l2b * 0.5f + dj * (p1b * (1.f/6.f) + di2 * (1.f/24.f)));
#pragma unroll
        for (int l = 0; l < 8; l++) { float dv = dr[l]; Sa[l] += ga * dv; Sb[l] += gb * dv; }
        l3a += dk * (l2a + dj * (p1a * 0.5f + di1 * (1.f/6.f)));
        l3b += dk * (l2b + dj * (p1b * 0.5f + di2 * (1.f/6.f)));
        l2a += (p1a + di1 * 0.5f) * dj;
        l2b += (p1b + di2 * 0.5f) * dj;
        p1a += di1; p1b += di2;
    }
    loc3[row1 * 9 + k1] = l3a;
    loc3[row2 * 9 + k1] = l3b;
    if (k1 == 0) { loc2[row1] = l2a; loc2[row2] = l2b; }
    if (jk == 0) { loc1[i1] = p1a; loc1[i2] = p1b; }
    __syncthreads();
    float a1 = sA[i1], a2 = sA[8 + row1], a3 = sA[P3OFF + row1 * 9 + k1];
    float c1_ = sA[i2], c2_ = sA[8 + row2], c3_ = sA[P3OFF + row2 * 9 + k1];
    const float* l3p = &loc3[jk * 9];
    const float* l2p = &loc2[k1 * 8];
    float n4a[8], n4b[8];
#pragma unroll
    for (int l = 0; l < 8; l++) {
        float v3 = l3p[l], v2 = l2p[l], v1 = loc1[l];
        n4a[l] = sA[P4OFF + tid * 9 + l]  + Sa[l] + a1 * v3 + a2 * v2 + a3 * v1;
        n4b[l] = sA[P4OFF + pos2 * 9 + l] + Sb[l] + c1_ * v3 + c2_ * v2 + c3_ * v1;
    }
    float n3a = a3 + l3a + a1 * loc2[jk] + a2 * loc1[k1];
    float n3b = c3_ + l3b + c1_ * loc2[jk] + c2_ * loc1[k1];
    float n2v = 0.f, n1v = 0.f;
    if (tid < 64) n2v = sA[8 + tid] + loc2[tid] + sA[tid >> 3] * loc1[tid & 7];
    if (tid < 8)  n1v = sA[tid] + loc1[tid];
    __syncthreads();
#pragma unroll
    for (int l = 0; l < 8; l++) { sA[P4OFF + tid * 9 + l] = n4a[l]; sA[P4OFF + pos2 * 9 + l] = n4b[l]; }
    sA[P3OFF + row1 * 9 + k1] = n3a;
    sA[P3OFF + row2 * 9 + k1] = n3b;
    if (tid < 64) sA[8 + tid] = n2v;
    if (tid < 8)  sA[tid] = n1v;
    __syncthreads();
}

// ------------------------------------------------ THE kernel: 5 roles, flag dataflow
// blocks [0,256): fold (b,g)     -> S rows (b*32+g)*4+c    | sets fflag[bid]
// blocks [256,384): scan (b,s)   -> P                      | waits 32 fflags, sets sflag
// blocks [384,1408): apply chunk -> partial row            | waits 16 sflags, sets aflag
// blocks [1408,1555): gemv kc    -> hpart                  | waits 1024 aflags, sets gflag
// blocks [1555,1563): final b    -> out                    | waits 147 gflags
__global__ __launch_bounds__(256) void mega_kernel(
    const float* __restrict__ x,  const float* __restrict__ W1,
    const float* __restrict__ b1, const float* __restrict__ W2,
    const float* __restrict__ b2, float* __restrict__ outp,
    float* __restrict__ S, float* __restrict__ P,
    float* __restrict__ partial, float* __restrict__ hpart,
    unsigned* __restrict__ flags)
{
    const int bid = blockIdx.x;
    const int tid = threadIdx.x;

    __shared__ __attribute__((aligned(16))) float smem[6656];   // 26 KB, role-aliased

    unsigned* fflag = flags;          // 256
    unsigned* sflag = flags + 256;    // 128
    unsigned* aflag = flags + 384;    // 1024
    unsigned* gflag = flags + 1408;   // 147

    const int i1 = tid >> 6, j1 = (tid >> 3) & 7, k1 = tid & 7;
    const int row1 = tid >> 3, row2 = row1 + 32;
    const int jk = tid & 63;
    const int pos2 = tid + 256, i2 = pos2 >> 6;

    if (bid < 256) {
        // ---------------- fold role ------------------------------------------
        float* sInc = smem;            // 512
        float* sA   = smem + 512;      // 5256
        float* U    = smem + 5768;     // 648 (ends 6416)
        const int b = bid >> 5, g = bid & 31;
        load_inc(x, b, g, sInc, tid);
        for (int m = tid; m < SIGSZ; m += 256) sA[m] = 0.f;
        __syncthreads();
        for (int c = 0; c < 4; c++) {
            chunk_step(&sInc[c * 128], sA, U, tid);
            // sA stable until next chunk_step's 2nd barrier: race-free reads.
            float* Sr = S + ((size_t)bid * 4 + c) * MEM;
            for (int m = tid; m < MEM; m += 256) {
                float v;
                if (m < 72) v = sA[m];
                else if (m < 584) { int e = m - 72;  v = sA[P3OFF + (e >> 3) * 9 + (e & 7)]; }
                else              { int e = m - 584; v = sA[P4OFF + (e >> 3) * 9 + (e & 7)]; }
                stc(Sr + m, v);
            }
        }
        __syncthreads();               // all waves' stc stores vmcnt-drained
        if (tid == 0) stu(&fflag[bid], 1u);
        return;
    }

    if (bid < 384) {
        // ---------------- scan role ------------------------------------------
        float* st1 = smem;             // 32*8
        float* st2 = smem + 256;       // 32*64
        float* st3 = smem + 2304;      // 32*32
        float* sp1 = smem + 3328;      // 32*8
        float* sp2 = smem + 3584;      // 32*64
        float* sp3 = smem + 5632;      // 32*32 (ends 6656)
        const int sb = bid - 256;
        const int b2 = sb >> 4, s = sb & 15;
        const int bBase = b2 * NG;

        if (tid < 32) waitflag(fflag + bBase + tid);
        __syncthreads();

        const int jkl   = ((s & 1) << 8) | tid;
        const int m4idx = s * 256 + tid;

        float rL4[NG], rL3[NG];
#pragma unroll
        for (int gg = 0; gg < NG; gg++) {
            const float* Trow = S + ((size_t)(bBase + gg) * 4 + 3) * MEM;
            rL4[gg] = ldc(Trow + 584 + m4idx);
            rL3[gg] = ldc(Trow + 72 + jkl);
        }
        {
            int gg = tid >> 3, i = tid & 7;
            st1[gg * 8 + i] = ldc(S + ((size_t)(bBase + gg) * 4 + 3) * MEM + i);
        }
        for (int m = tid; m < NG * 64; m += 256) {
            int gg = m >> 6, e = m & 63;
            st2[gg * 64 + e] = ldc(S + ((size_t)(bBase + gg) * 4 + 3) * MEM + 8 + e);
        }
        for (int m = tid; m < NG * 32; m += 256) {
            int gg = m >> 5, e = m & 31;
            st3[gg * 32 + e] = ldc(S + ((size_t)(bBase + gg) * 4 + 3) * MEM + 72 + s * 32 + e);
        }
        __syncthreads();

        if (tid < 64) {
            int i = tid >> 3, k = tid & 7;
            float p1acc = 0.f, p2acc = 0.f;
            for (int gg = 0; gg < NG; gg++) {
                sp2[gg * 64 + tid] = p2acc;
                if (k == 0) sp1[gg * 8 + i] = p1acc;
                if (s == 0) {
                    float* prow = P + (size_t)(bBase + gg) * MEM;
                    stc(prow + 8 + tid, p2acc);
                    if (k == 0) stc(prow + i, p1acc);
                }
                p2acc += st2[gg * 64 + tid] + p1acc * st1[gg * 8 + k];
                p1acc += st1[gg * 8 + i];
            }
        }
        __syncthreads();
        if (tid < 32) {
            int ijk = s * 32 + tid;
            int i = ijk >> 6, jk2 = ijk & 63, ij = ijk >> 3, k = ijk & 7;
            float acc3 = 0.f;
            for (int gg = 0; gg < NG; gg++) {
                sp3[gg * 32 + tid] = acc3;
                stc(P + (size_t)(bBase + gg) * MEM + 72 + ijk, acc3);
                acc3 += st3[gg * 32 + tid] + sp1[gg * 8 + i] * st2[gg * 64 + jk2]
                      + sp2[gg * 64 + ij] * st1[gg * 8 + k];
            }
        }
        __syncthreads();
        {
            const int i  = s >> 1;
            const int ij = (s << 2) + (tid >> 6);
            const int kl = tid & 63, l = tid & 7, p3 = tid >> 3;
            float acc4 = 0.f;
            size_t prowBase = (size_t)bBase * MEM + 584 + m4idx;
#pragma unroll
            for (int gg = 0; gg < NG; gg++) {
                stc(P + prowBase + (size_t)gg * MEM, acc4);
                acc4 += rL4[gg] + sp1[gg * 8 + i] * rL3[gg]
                      + sp2[gg * 64 + ij] * st2[gg * 64 + kl]
                      + sp3[gg * 32 + p3] * st1[gg * 8 + l];
            }
        }
        __syncthreads();
        if (tid == 0) stu(&sflag[sb], 1u);
        return;
    }

    if (bid < 1408) {
        // ---------------- apply role (per chunk) -----------------------------
        float* sA = smem;              // 5256
        float* sR = smem + 5256;       // 648 (ends 5904)
        const int blk = bid - 384;                // (b*32+g)*4 + c
        const int bb = blk >> 7;                  // batch
        const float* Prow = P + (size_t)(blk >> 2) * MEM;
        const float* Srow = S + (size_t)blk * MEM;

        if (tid < 16) waitflag(sflag + bb * 16 + tid);
        __syncthreads();

        float a1  = ldc(Prow + i1);
        float a2  = ldc(Prow + 8 + row1);
        float a3  = ldc(Prow + 72 + tid);
        float c1_ = ldc(Prow + i2);
        float c2_ = ldc(Prow + 8 + row2);
        float c3_ = ldc(Prow + 72 + 256 + tid);
        float pP4a[8], pP4b[8];
#pragma unroll
        for (int l = 0; l < 8; l++) {
            pP4a[l] = ldc(Prow + 584 + tid * 8 + l);
            pP4b[l] = ldc(Prow + 584 + (tid + 256) * 8 + l);
        }
        const float p2v = (tid < 64) ? ldc(Prow + 8 + tid) : 0.f;
        const float p1v = (tid < 8) ? ldc(Prow + tid) : 0.f;
        const float p2i = ldc(Prow + (tid >> 3));

        for (int m = tid; m < MEM; m += 256) {
            float v = ldc(Srow + m);
            if (m < 72) sA[m] = v;
            else if (m < 584) { int e = m - 72;  sA[P3OFF + (e >> 3) * 9 + (e & 7)] = v; }
            else              { int e = m - 584; sA[P4OFF + (e >> 3) * 9 + (e & 7)] = v; }
        }
        __syncthreads();

        const float* q3p = &sA[P3OFF + jk * 9];
        const float* q2p = &sA[8 + k1 * 8];
        float R4a[8], R4b[8];
#pragma unroll
        for (int l = 0; l < 8; l++) {
            float v3 = q3p[l], v2 = q2p[l], v1 = sA[l];
            R4a[l] = pP4a[l] + sA[P4OFF + tid * 9 + l]  + a1 * v3 + a2 * v2 + a3 * v1;
            R4b[l] = pP4b[l] + sA[P4OFF + pos2 * 9 + l] + c1_ * v3 + c2_ * v2 + c3_ * v1;
        }
        float R3a = a3  + sA[P3OFF + row1 * 9 + k1] + a1  * sA[8 + jk] + a2  * sA[k1];
        float R3b = c3_ + sA[P3OFF + row2 * 9 + k1] + c1_ * sA[8 + jk] + c2_ * sA[k1];
        float R2v = 0.f, R1v = 0.f;
        if (tid < 64) R2v = p2v + sA[8 + tid] + p2i * sA[tid & 7];
        if (tid < 8)  R1v = p1v + sA[tid];

        sR[P3OFF + row1 * 9 + k1] = R3a;
        sR[P3OFF + row2 * 9 + k1] = R3b;
        if (tid < 64) sR[8 + tid] = R2v;
        if (tid < 8)  sR[tid] = R1v;
        __syncthreads();

        float q23a = sR[i1] * sR[8 + jk] + sR[8 + row1] * sR[k1];
        float q23b = sR[i2] * sR[8 + jk] + sR[8 + row2] * sR[k1];
        float pool4a[8], pool4b[8];
        float pool3a, pool3b, pool2 = 0.f, pool1 = 0.f;
        {
            float s1ia = sR[i1], s1ib = sR[i2], s1j = sR[j1], s1k = sR[k1];
            float s2ija = sR[8 + row1], s2ijb = sR[8 + row2];
            float s2jk = sR[8 + jk];
            const float* r3p = &sR[P3OFF + jk * 9];
            const float* r2p = &sR[8 + k1 * 8];
#pragma unroll
            for (int l = 0; l < 8; l++) {
                float s1l = sR[l];
                float p22 = s1k * s1l;
                float q23l = s1j * r2p[l] + s2jk * s1l;
                float p24a = s1ia * r3p[l] + s2ija * r2p[l] + R3a * s1l;
                float p24b = s1ib * r3p[l] + s2ijb * r2p[l] + R3b * s1l;
                float p34a = s1ia * q23l + s2ija * p22;
                float p34b = s1ib * q23l + s2ijb * p22;
                float p44a = s1ia * s1j * p22;
                float p44b = s1ib * s1j * p22;
                pool4a[l] = R4a[l] - 0.5f * p24a + (1.f/3.f) * p34a - 0.25f * p44a;
                pool4b[l] = R4b[l] - 0.5f * p24b + (1.f/3.f) * p34b - 0.25f * p44b;
            }
            pool3a = R3a - 0.5f * q23a + (1.f/3.f) * s1ia * s1j * s1k;
            pool3b = R3b - 0.5f * q23b + (1.f/3.f) * s1ib * s1j * s1k;
            if (tid < 64) pool2 = R2v - 0.5f * sR[tid >> 3] * sR[tid & 7];
            if (tid < 8)  pool1 = R1v;
        }

        float* pb = partial + (size_t)blk * MEM;
#pragma unroll
        for (int l = 0; l < 8; l++) {
            stc(pb + 584 + tid * 8 + l, pool4a[l]);
            stc(pb + 584 + (tid + 256) * 8 + l, pool4b[l]);
        }
        stc(pb + 72 + tid, pool3a);
        stc(pb + 72 + 256 + tid, pool3b);
        if (tid < 64) stc(pb + 8 + tid, pool2);
        if (tid < 8)  stc(pb + tid, pool1);
        __syncthreads();
        if (tid == 0) stu(&aflag[blk], 1u);
        return;
    }

    if (bid < 1555) {
        // ---------------- gemv role ------------------------------------------
        float* sp = smem;              // 8*32
        const int kc = bid - 1408;
        const int k0 = kc * 32;

        // needs ALL 1024 apply rows: each thread waits 4 flags
        waitflag(aflag + tid * 4 + 0);
        waitflag(aflag + tid * 4 + 1);
        waitflag(aflag + tid * 4 + 2);
        waitflag(aflag + tid * 4 + 3);
        __syncthreads();

        {
            int bb = tid >> 5, k = tid & 31;
            float sum = 0.f;
            if (k0 + k < MEM) {
                const float* pp = partial + (size_t)bb * 128 * MEM + k0 + k;
#pragma unroll 8
                for (int n = 0; n < 128; n++) sum += ldc(pp + (size_t)n * MEM);
            }
            sp[bb * 32 + k] = sum * (1.f / 128.f);
        }
        __syncthreads();
        float acc[8];
#pragma unroll
        for (int b = 0; b < 8; b++) acc[b] = 0.f;
        int kend = (k0 + 32 < MEM) ? 32 : (MEM - k0);
        for (int k = 0; k < kend; k++) {
            float wv = W1[(size_t)(k0 + k) * 256 + tid];
#pragma unroll
            for (int b = 0; b < 8; b++) acc[b] += sp[b * 32 + k] * wv;
        }
#pragma unroll
        for (int b = 0; b < 8; b++) stc(hpart + (size_t)kc * 2048 + b * 256 + tid, acc[b]);
        __syncthreads();
        if (tid == 0) stu(&gflag[kc], 1u);
        return;
    }

    {
        // ---------------- final role -----------------------------------------
        float* sRed = smem;
        const int b = bid - 1555;
        if (tid < 147) waitflag(gflag + tid);
        __syncthreads();
        float v = 0.f;
#pragma unroll 7
        for (int kc = 0; kc < 147; kc++) v += ldc(hpart + (size_t)kc * 2048 + b * 256 + tid);
        v += b1[tid];
        v = fmaxf(v, 0.f) * W2[tid];
        sRed[tid] = v;
        __syncthreads();
        for (int s = 128; s > 0; s >>= 1) {
            if (tid < s) sRed[tid] += sRed[tid + s];
            __syncthreads();
        }
        if (tid == 0) outp[b] = sRed[0] + b2[0];
    }
}

// ------------------------------------------------ launch
extern "C" void kernel_launch(void* const* d_in, const int* in_sizes, int n_in,
                              void* d_out, int out_size, void* d_ws, size_t ws_size,
                              hipStream_t stream) {
    const float* x  = (const float*)d_in[0];
    const float* W1 = (const float*)d_in[1];
    const float* b1 = (const float*)d_in[2];
    const float* W2 = (const float*)d_in[3];
    const float* b2 = (const float*)d_in[4];
    float* out = (float*)d_out;

    float* ws = (float*)d_ws;
    float* S       = ws;                             // 1024*MEM (4 snapshots/group; c=3 = totals)
    float* P       = S + (size_t)1024 * MEM;         // 256*MEM  (exclusive group prefixes)
    float* partial = P + (size_t)256 * MEM;          // 1024*MEM (per-chunk pooled rows)
    float* hpart   = partial + (size_t)1024 * MEM;   // 147*2048 (gemv partials)
    size_t flagoff = (size_t)1024 * MEM * 2 + (size_t)256 * MEM + (size_t)147 * 2048;
    flagoff = (flagoff + 31) & ~(size_t)31;
    unsigned* flags = (unsigned*)(ws + flagoff);     // 1555 flags (fold|scan|apply|gemv)

    // workspace is poisoned each iteration: flags MUST be zeroed. Stream-ordered.
    hipMemsetAsync(flags, 0, 8192, stream);
    mega_kernel<<<1563, 256, 0, stream>>>(x, W1, b1, W2, b2, out, S, P, partial, hpart, flags);
}

// Round 9
// 126.071 us; speedup vs baseline: 1.4342x; 1.4342x over previous
//
#include <hip/hip_runtime.h>

// BLAMem: truncated tensor-algebra (depth 4, C=8) log-signature memory.
// Round-16: fold+apply FUSED PER BLOCK (snapshots never leave LDS), flag dataflow.
// Evidence chain: R7 mega (separate fold/apply blocks) correct but 137us -- 205MB
// uncached traffic for 44MB logical, dominated by the S and per-chunk partial
// buffers that exist ONLY because apply ran in foreign blocks. This round: grid=256,
// 1 block/CU (110KB LDS; 256-block co-residency at 120KB proven in R2/R3), each
// block folds its group keeping 4 snapshots in LDS, blocks 0..127 also scan, then
// every block applies its own group's prefix to its LDS snapshots. Cross-block
// buffers shrink to T/P/partial/hpart ~16MB, all coalesced (stride-8 L4 paths
// staged through LDS both directions). Sync = R7-validated fence-free sc0sc1 flags
// with ~40ms timeouts (any bug => wrong answer, never a hang).
// FP summation orders verbatim from verified rounds: fold/snap R2, scan R7,
// apply R5, gemv R0 (per-group rows, g ascending), final R0. NO atomic RMW.

#define MEM   4680   // 8 + 64 + 512 + 4096 (unpadded global layout)
#define NG    32     // groups per batch
#define TLEN  2048

#define P3OFF 72
#define P4OFF 648
#define SIGSZ 5256

// Coherence-point accessors (SYSTEM scope => sc0 sc1: bypass L1+L2, no fences).
__device__ __forceinline__ float ldc(const float* p) {
    return __hip_atomic_load(p, __ATOMIC_RELAXED, __HIP_MEMORY_SCOPE_SYSTEM);
}
__device__ __forceinline__ void stc(float* p, float v) {
    __hip_atomic_store(p, v, __ATOMIC_RELAXED, __HIP_MEMORY_SCOPE_SYSTEM);
}
__device__ __forceinline__ unsigned ldu(const unsigned* p) {
    return __hip_atomic_load(p, __ATOMIC_RELAXED, __HIP_MEMORY_SCOPE_SYSTEM);
}
__device__ __forceinline__ void stu(unsigned* p, unsigned v) {
    __hip_atomic_store(p, v, __ATOMIC_RELAXED, __HIP_MEMORY_SCOPE_SYSTEM);
}
#define SPIN_TIMEOUT 4000000ull   // ~40ms

__device__ __forceinline__ void waitflag(const unsigned* f) {
    unsigned long long t0 = __builtin_amdgcn_s_memrealtime();
    while (ldu(f) == 0u) {
        __builtin_amdgcn_s_sleep(8);
        if (__builtin_amdgcn_s_memrealtime() - t0 > SPIN_TIMEOUT) break;
    }
}

// smem layout (floats): sSnap [0,21024) persistent through apply.
// Aliased region @21024: fold {sInc 512 @21024, U 648 @21536};
// scan {scanBuf 6656 @21024}; apply {sR 648 @21024, sG 4096 @21672};
// gemv {sp 256 @21024}; final {sRed 256 @21024}. Total 27680 floats = 110.7KB.
#define SMEM_TOTAL 27680

__global__ __launch_bounds__(256) void mega_kernel(
    const float* __restrict__ x,  const float* __restrict__ W1,
    const float* __restrict__ b1, const float* __restrict__ W2,
    const float* __restrict__ b2, float* __restrict__ outp,
    float* __restrict__ T, float* __restrict__ P,
    float* __restrict__ partial, float* __restrict__ hpart,
    unsigned* __restrict__ flags)
{
    const int bid = blockIdx.x;
    const int tid = threadIdx.x;
    const int b = bid >> 5, g = bid & 31;

    __shared__ __attribute__((aligned(16))) float smem[SMEM_TOTAL];

    unsigned* fflag = flags;          // 256 fold-done
    unsigned* sflag = flags + 256;    // 128 scan-done
    unsigned* aflag = flags + 384;    // 256 apply-done
    unsigned* gflag = flags + 640;    // 147 gemv-done

    float* sSnap0 = smem;             // 4 x SIGSZ

    const int i1 = tid >> 6, j1 = (tid >> 3) & 7, k1 = tid & 7;
    const int row1 = tid >> 3, row2 = row1 + 32;
    const int jk = tid & 63;
    const int pos2 = tid + 256, i2 = pos2 >> 6;

    // ================= phase 1: fold (all 256 blocks), snapshots in LDS ========
    {
        float* sInc = smem + 21024;    // 512
        float* U    = smem + 21536;    // 648
        float* loc3 = U;
        float* loc2 = U + 576;
        float* loc1 = U + 640;

        for (int e = tid; e < 512; e += 256) {
            int s = e >> 3, c = e & 7;
            int t = g * 64 + s;
            float v;
            if (c < 7) {
                float cur  = x[(b * TLEN + t) * 7 + c];
                float prev = (t > 0) ? x[(b * TLEN + t - 1) * 7 + c] : 0.f;
                v = cur - prev;
            } else v = (t > 0) ? (1.f / 2047.f) : 0.f;
            sInc[e] = v;
        }
        __syncthreads();

        for (int c = 0; c < 4; ++c) {
            const float* dch = &sInc[c * 128];
            float p1a = 0.f, l2a = 0.f, l3a = 0.f, p1b = 0.f, l2b = 0.f, l3b = 0.f;
            float Sa[8], Sb[8];
#pragma unroll
            for (int l = 0; l < 8; l++) { Sa[l] = 0.f; Sb[l] = 0.f; }
#pragma unroll
            for (int t = 0; t < 16; t++) {
                const float* dr = dch + t * 8;
                float di1 = dr[i1], di2 = dr[i2], dj = dr[j1], dk = dr[k1];
                float ga = l3a + dk * (l2a * 0.5f + dj * (p1a * (1.f/6.f) + di1 * (1.f/24.f)));
                float gb = l3b + dk * (l2b * 0.5f + dj * (p1b * (1.f/6.f) + di2 * (1.f/24.f)));
#pragma unroll
                for (int l = 0; l < 8; l++) { float dv = dr[l]; Sa[l] += ga * dv; Sb[l] += gb * dv; }
                l3a += dk * (l2a + dj * (p1a * 0.5f + di1 * (1.f/6.f)));
                l3b += dk * (l2b + dj * (p1b * 0.5f + di2 * (1.f/6.f)));
                l2a += (p1a + di1 * 0.5f) * dj;
                l2b += (p1b + di2 * 0.5f) * dj;
                p1a += di1; p1b += di2;
            }
            loc3[row1 * 9 + k1] = l3a;
            loc3[row2 * 9 + k1] = l3b;
            if (k1 == 0) { loc2[row1] = l2a; loc2[row2] = l2b; }
            if (jk == 0) { loc1[i1] = p1a; loc1[i2] = p1b; }
            __syncthreads();

            float* dst = sSnap0 + c * SIGSZ;
            const float* l3p = &loc3[jk * 9];
            const float* l2p = &loc2[k1 * 8];
            if (c == 0) {
#pragma unroll
                for (int l = 0; l < 8; l++) { dst[P4OFF + tid * 9 + l] = Sa[l]; dst[P4OFF + pos2 * 9 + l] = Sb[l]; }
                dst[P3OFF + row1 * 9 + k1] = l3a;
                dst[P3OFF + row2 * 9 + k1] = l3b;
                if (tid < 64) dst[8 + tid] = loc2[tid];
                if (tid < 8)  dst[tid] = loc1[tid];
            } else {
                const float* prv = sSnap0 + (c - 1) * SIGSZ;
                float a1 = prv[i1], a2 = prv[8 + row1], a3 = prv[P3OFF + row1 * 9 + k1];
                float c1_ = prv[i2], c2_ = prv[8 + row2], c3_ = prv[P3OFF + row2 * 9 + k1];
#pragma unroll
                for (int l = 0; l < 8; l++) {
                    float v3 = l3p[l], v2 = l2p[l], v1 = loc1[l];
                    dst[P4OFF + tid * 9 + l]  = prv[P4OFF + tid * 9 + l]  + Sa[l] + a1 * v3 + a2 * v2 + a3 * v1;
                    dst[P4OFF + pos2 * 9 + l] = prv[P4OFF + pos2 * 9 + l] + Sb[l] + c1_ * v3 + c2_ * v2 + c3_ * v1;
                }
                dst[P3OFF + row1 * 9 + k1] = a3 + l3a + a1 * loc2[jk] + a2 * loc1[k1];
                dst[P3OFF + row2 * 9 + k1] = c3_ + l3b + c1_ * loc2[jk] + c2_ * loc1[k1];
                if (tid < 64) dst[8 + tid] = prv[8 + tid] + loc2[tid] + prv[tid >> 3] * loc1[tid & 7];
                if (tid < 8)  dst[tid] = prv[tid] + loc1[tid];
            }
            __syncthreads();
        }

        // group total (snapshot 3) -> T, coalesced write-through
        {
            const float* s3 = sSnap0 + 3 * SIGSZ;
            float* Tr = T + (size_t)bid * MEM;
            for (int m = tid; m < MEM; m += 256) {
                float v;
                if (m < 72) v = s3[m];
                else if (m < 584) { int e = m - 72;  v = s3[P3OFF + (e >> 3) * 9 + (e & 7)]; }
                else              { int e = m - 584; v = s3[P4OFF + (e >> 3) * 9 + (e & 7)]; }
                stc(Tr + m, v);
            }
        }
        __syncthreads();               // all waves' stc stores vmcnt-drained
        if (tid == 0) stu(&fflag[bid], 1u);
    }

    // ================= phase 2: scan (blocks 0..127) ===========================
    if (bid < 128) {
        float* st1 = smem + 21024;             // 32*8
        float* st2 = smem + 21024 + 256;       // 32*64
        float* st3 = smem + 21024 + 2304;      // 32*32
        float* sp1 = smem + 21024 + 3328;      // 32*8
        float* sp2 = smem + 21024 + 3584;      // 32*64
        float* sp3 = smem + 21024 + 5632;      // 32*32
        const int b2 = bid >> 4, s = bid & 15;
        const int bBase = b2 * NG;

        if (tid < 32) waitflag(fflag + bBase + tid);
        __syncthreads();

        const int jkl   = ((s & 1) << 8) | tid;
        const int m4idx = s * 256 + tid;

        float rL4[NG], rL3[NG];
#pragma unroll
        for (int gg = 0; gg < NG; gg++) {
            const float* Trow = T + (size_t)(bBase + gg) * MEM;
            rL4[gg] = ldc(Trow + 584 + m4idx);
            rL3[gg] = ldc(Trow + 72 + jkl);
        }
        {
            int gg = tid >> 3, i = tid & 7;
            st1[gg * 8 + i] = ldc(T + (size_t)(bBase + gg) * MEM + i);
        }
        for (int m = tid; m < NG * 64; m += 256) {
            int gg = m >> 6, e = m & 63;
            st2[gg * 64 + e] = ldc(T + (size_t)(bBase + gg) * MEM + 8 + e);
        }
        for (int m = tid; m < NG * 32; m += 256) {
            int gg = m >> 5, e = m & 31;
            st3[gg * 32 + e] = ldc(T + (size_t)(bBase + gg) * MEM + 72 + s * 32 + e);
        }
        __syncthreads();

        if (tid < 64) {
            int i = tid >> 3, k = tid & 7;
            float p1acc = 0.f, p2acc = 0.f;
            for (int gg = 0; gg < NG; gg++) {
                sp2[gg * 64 + tid] = p2acc;
                if (k == 0) sp1[gg * 8 + i] = p1acc;
                if (s == 0) {
                    float* prow = P + (size_t)(bBase + gg) * MEM;
                    stc(prow + 8 + tid, p2acc);
                    if (k == 0) stc(prow + i, p1acc);
                }
                p2acc += st2[gg * 64 + tid] + p1acc * st1[gg * 8 + k];
                p1acc += st1[gg * 8 + i];
            }
        }
        __syncthreads();
        if (tid < 32) {
            int ijk = s * 32 + tid;
            int i = ijk >> 6, jk2 = ijk & 63, ij = ijk >> 3, k = ijk & 7;
            float acc3 = 0.f;
            for (int gg = 0; gg < NG; gg++) {
                sp3[gg * 32 + tid] = acc3;
                stc(P + (size_t)(bBase + gg) * MEM + 72 + ijk, acc3);
                acc3 += st3[gg * 32 + tid] + sp1[gg * 8 + i] * st2[gg * 64 + jk2]
                      + sp2[gg * 64 + ij] * st1[gg * 8 + k];
            }
        }
        __syncthreads();
        {
            const int i  = s >> 1;
            const int ij = (s << 2) + (tid >> 6);
            const int kl = tid & 63, l = tid & 7, p3 = tid >> 3;
            float acc4 = 0.f;
            size_t prowBase = (size_t)bBase * MEM + 584 + m4idx;
#pragma unroll
            for (int gg = 0; gg < NG; gg++) {
                stc(P + prowBase + (size_t)gg * MEM, acc4);
                acc4 += rL4[gg] + sp1[gg * 8 + i] * rL3[gg]
                      + sp2[gg * 64 + ij] * st2[gg * 64 + kl]
                      + sp3[gg * 32 + p3] * st1[gg * 8 + l];
            }
        }
        __syncthreads();
        if (tid == 0) stu(&sflag[bid], 1u);
    }

    // ================= phase 3: apply own group (all 256 blocks) ===============
    {
        float* sR = smem + 21024;      // 648
        float* sG = smem + 21672;      // 4096
        const float* Prow = P + (size_t)bid * MEM;

        if (tid < 16) waitflag(sflag + b * 16 + tid);
        __syncthreads();

        // coalesced uncached stage of P L4 into LDS, then per-thread gather
        for (int m = tid; m < 4096; m += 256) sG[m] = ldc(Prow + 584 + m);
        const float a1  = ldc(Prow + i1);
        const float a2  = ldc(Prow + 8 + row1);
        const float a3  = ldc(Prow + 72 + tid);
        const float c1_ = ldc(Prow + i2);
        const float c2_ = ldc(Prow + 8 + row2);
        const float c3_ = ldc(Prow + 72 + 256 + tid);
        const float p2v = (tid < 64) ? ldc(Prow + 8 + tid) : 0.f;
        const float p1v = (tid < 8) ? ldc(Prow + tid) : 0.f;
        const float p2i = ldc(Prow + (tid >> 3));
        __syncthreads();               // sG ready

        float pP4a[8], pP4b[8];
#pragma unroll
        for (int l = 0; l < 8; l++) {
            pP4a[l] = sG[tid * 8 + l];
            pP4b[l] = sG[(tid + 256) * 8 + l];
        }
        __syncthreads();               // gathers complete; sG reusable later

        float pool4a[8], pool4b[8];
#pragma unroll
        for (int l = 0; l < 8; l++) { pool4a[l] = 0.f; pool4b[l] = 0.f; }
        float pool3a = 0.f, pool3b = 0.f, pool2 = 0.f, pool1 = 0.f;

        for (int c = 0; c < 4; ++c) {
            const float* sAc = sSnap0 + c * SIGSZ;
            const float* q3p = &sAc[P3OFF + jk * 9];
            const float* q2p = &sAc[8 + k1 * 8];
            float R4a[8], R4b[8];
#pragma unroll
            for (int l = 0; l < 8; l++) {
                float v3 = q3p[l], v2 = q2p[l], v1 = sAc[l];
                R4a[l] = pP4a[l] + sAc[P4OFF + tid * 9 + l]  + a1 * v3 + a2 * v2 + a3 * v1;
                R4b[l] = pP4b[l] + sAc[P4OFF + pos2 * 9 + l] + c1_ * v3 + c2_ * v2 + c3_ * v1;
            }
            float R3a = a3  + sAc[P3OFF + row1 * 9 + k1] + a1  * sAc[8 + jk] + a2  * sAc[k1];
            float R3b = c3_ + sAc[P3OFF + row2 * 9 + k1] + c1_ * sAc[8 + jk] + c2_ * sAc[k1];
            float R2v = 0.f, R1v = 0.f;
            if (tid < 64) R2v = p2v + sAc[8 + tid] + p2i * sAc[tid & 7];
            if (tid < 8)  R1v = p1v + sAc[tid];

            sR[P3OFF + row1 * 9 + k1] = R3a;
            sR[P3OFF + row2 * 9 + k1] = R3b;
            if (tid < 64) sR[8 + tid] = R2v;
            if (tid < 8)  sR[tid] = R1v;
            __syncthreads();

            float q23a = sR[i1] * sR[8 + jk] + sR[8 + row1] * sR[k1];
            float q23b = sR[i2] * sR[8 + jk] + sR[8 + row2] * sR[k1];
            {
                float s1ia = sR[i1], s1ib = sR[i2], s1j = sR[j1], s1k = sR[k1];
                float s2ija = sR[8 + row1], s2ijb = sR[8 + row2];
                float s2jk = sR[8 + jk];
                const float* r3p = &sR[P3OFF + jk * 9];
                const float* r2p = &sR[8 + k1 * 8];
#pragma unroll
                for (int l = 0; l < 8; l++) {
                    float s1l = sR[l];
                    float p22 = s1k * s1l;
                    float q23l = s1j * r2p[l] + s2jk * s1l;
                    float p24a = s1ia * r3p[l] + s2ija * r2p[l] + R3a * s1l;
                    float p24b = s1ib * r3p[l] + s2ijb * r2p[l] + R3b * s1l;
                    float p34a = s1ia * q23l + s2ija * p22;
                    float p34b = s1ib * q23l + s2ijb * p22;
                    float p44a = s1ia * s1j * p22;
                    float p44b = s1ib * s1j * p22;
                    pool4a[l] += R4a[l] - 0.5f * p24a + (1.f/3.f) * p34a - 0.25f * p44a;
                    pool4b[l] += R4b[l] - 0.5f * p24b + (1.f/3.f) * p34b - 0.25f * p44b;
                }
                pool3a += R3a - 0.5f * q23a + (1.f/3.f) * s1ia * s1j * s1k;
                pool3b += R3b - 0.5f * q23b + (1.f/3.f) * s1ib * s1j * s1k;
                if (tid < 64) pool2 += R2v - 0.5f * sR[tid >> 3] * sR[tid & 7];
                if (tid < 8)  pool1 += R1v;
            }
            __syncthreads();
        }

        // stage pool4 into sG, then coalesced uncached stores of the partial row
#pragma unroll
        for (int l = 0; l < 8; l++) {
            sG[tid * 8 + l] = pool4a[l];
            sG[(tid + 256) * 8 + l] = pool4b[l];
        }
        __syncthreads();
        float* pb = partial + (size_t)bid * MEM;
        for (int m = tid; m < 4096; m += 256) stc(pb + 584 + m, sG[m]);
        stc(pb + 72 + tid, pool3a);
        stc(pb + 72 + 256 + tid, pool3b);
        if (tid < 64) stc(pb + 8 + tid, pool2);
        if (tid < 8)  stc(pb + tid, pool1);
        __syncthreads();               // vmcnt drained
        if (tid == 0) stu(&aflag[bid], 1u);
    }

    if (bid >= 147) return;

    // ================= phase 4: gemv (blocks 0..146) ===========================
    {
        float* sp = smem + 21024;      // 8*32
        const int kc = bid;
        const int k0 = kc * 32;

        waitflag(aflag + tid);         // all 256 apply rows
        __syncthreads();

        {
            int bb = tid >> 5, k = tid & 31;
            float sum = 0.f;
            if (k0 + k < MEM) {
                const float* pp = partial + (size_t)(bb * NG) * MEM + k0 + k;
                for (int gg = 0; gg < NG; gg++) sum += ldc(pp + (size_t)gg * MEM);
            }
            sp[bb * 32 + k] = sum * (1.f / 128.f);
        }
        __syncthreads();
        float acc[8];
#pragma unroll
        for (int bb = 0; bb < 8; bb++) acc[bb] = 0.f;
        int kend = (k0 + 32 < MEM) ? 32 : (MEM - k0);
        for (int k = 0; k < kend; k++) {
            float wv = W1[(size_t)(k0 + k) * 256 + tid];
#pragma unroll
            for (int bb = 0; bb < 8; bb++) acc[bb] += sp[bb * 32 + k] * wv;
        }
#pragma unroll
        for (int bb = 0; bb < 8; bb++) stc(hpart + (size_t)kc * 2048 + bb * 256 + tid, acc[bb]);
        __syncthreads();
        if (tid == 0) stu(&gflag[kc], 1u);
    }

    if (bid >= 8) return;

    // ================= phase 5: final (blocks 0..7) ============================
    {
        float* sRed = smem + 21024;
        if (tid < 147) waitflag(gflag + tid);
        __syncthreads();
        float v = 0.f;
#pragma unroll 7
        for (int kc = 0; kc < 147; kc++) v += ldc(hpart + (size_t)kc * 2048 + bid * 256 + tid);
        v += b1[tid];
        v = fmaxf(v, 0.f) * W2[tid];
        sRed[tid] = v;
        __syncthreads();
        for (int s = 128; s > 0; s >>= 1) {
            if (tid < s) sRed[tid] += sRed[tid + s];
            __syncthreads();
        }
        if (tid == 0) outp[bid] = sRed[0] + b2[0];
    }
}

// ------------------------------------------------ launch
extern "C" void kernel_launch(void* const* d_in, const int* in_sizes, int n_in,
                              void* d_out, int out_size, void* d_ws, size_t ws_size,
                              hipStream_t stream) {
    const float* x  = (const float*)d_in[0];
    const float* W1 = (const float*)d_in[1];
    const float* b1 = (const float*)d_in[2];
    const float* W2 = (const float*)d_in[3];
    const float* b2 = (const float*)d_in[4];
    float* out = (float*)d_out;

    float* ws = (float*)d_ws;
    float* T       = ws;                            // 256*MEM (group totals)
    float* P       = T + (size_t)256 * MEM;         // 256*MEM (exclusive group prefixes)
    float* partial = P + (size_t)256 * MEM;         // 256*MEM (per-group pooled rows)
    float* hpart   = partial + (size_t)256 * MEM;   // 147*2048 (gemv partials)
    size_t flagoff = (size_t)256 * MEM * 3 + (size_t)147 * 2048;
    flagoff = (flagoff + 31) & ~(size_t)31;
    unsigned* flags = (unsigned*)(ws + flagoff);    // 787 flags

    // workspace is poisoned each iteration: flags MUST be zeroed. Stream-ordered.
    hipMemsetAsync(flags, 0, 4096, stream);
    mega_kernel<<<256, 256, 0, stream>>>(x, W1, b1, W2, b2, out, T, P, partial, hpart, flags);
}